// Round 1
// baseline (1032.568 us; speedup 1.0000x reference)
//
#include <hip/hip_runtime.h>
#include <stdint.h>

// SIREN batched MLP, MI355X/gfx950.
// B=32 nets, N=32768 pts, layers: 2->128 (sin), 3x 128->128 (sin), 128->3.
// Precision plan (chaos gain ~4.8x/layer):
//   L1: fp32 VALU (exact-ish)
//   L2, L3: fp16 hi/lo split, 3x mfma_f32_32x32x16_f16 (residual ~2^-22)
//   L4: plain fp16 MFMA (budgeted: ~1.6e-4 rms at output)
//   L5: fp32 VALU from hi+lo reconstruct
// Predicted output absmax ~1e-3 vs threshold 1.67e-2.

typedef _Float16 f16x8 __attribute__((ext_vector_type(8)));
typedef float f32x16 __attribute__((ext_vector_type(16)));

#define B_ 32
#define N_ 32768
#define TN 64
#define NTHR 128

// flat param offsets (floats)
#define OFF_W1 0
#define OFF_B1 256
#define OFF_W2 384
#define OFF_B2 16768
#define OFF_W3 16896
#define OFF_B3 33280
#define OFF_W4 33408
#define OFF_B4 49792
#define OFF_W5 49920
#define OFF_B5 50304
#define NPARAM 50307

#define IMG_BYTES 4096           // one 16-wide K chunk image (hi or lo): 128 rows x 16 f16
#define CHUNKS 8
#define NLAYER 3
#define WHI_TOTAL ((size_t)B_ * NLAYER * CHUNKS * IMG_BYTES)   // 3,145,728 B

// sin(30*x) via v_sin_f32 (input in revolutions)
__device__ __forceinline__ float fast_sin30(float v) {
    float t = v * 4.77464829275686f;   // 30 / (2*pi)
    t = t - floorf(t);
    return __builtin_amdgcn_sinf(t);
}

// ---------------------------------------------------------------------------
// Pre-kernel: split W2/W3/W4 into fp16 hi/lo, written as swizzled chunk images.
// Image layout (per b, layer, chunk): row-pack = j>>2 (128 B), granule pos =
// ((j&3)*2 + g) ^ ((j>>2)&7), g = (k&15)>>3. Matches main-kernel B-frag reads.
// ---------------------------------------------------------------------------
__global__ __launch_bounds__(256) void siren_split(const float* __restrict__ params,
                                                   char* __restrict__ ws) {
    int tid = blockIdx.x * 256 + threadIdx.x;     // 196608 total
    int g  = tid & 15;                            // granule of 8 k
    int j  = (tid >> 4) & 127;                    // out-feature row
    int bl = tid >> 11;                           // b*3 + l
    int l  = bl % 3;
    int b  = bl / 3;
    int wOff = 384 + l * 16512;                   // W2/W3/W4 offsets
    const float* src = params + (size_t)b * NPARAM + wOff + j * 128 + g * 8;
    f16x8 hv, lv;
#pragma unroll
    for (int e = 0; e < 8; ++e) {
        float w = src[e];
        _Float16 h = (_Float16)w;
        hv[e] = h;
        lv[e] = (_Float16)(w - (float)h);
    }
    int c  = g >> 1;
    int gg = g & 1;
    int pos = ((j & 3) * 2 + gg) ^ ((j >> 2) & 7);
    size_t off = ((size_t)(b * NLAYER + l) * CHUNKS + c) * IMG_BYTES
               + (j >> 2) * 128 + pos * 16;
    *(f16x8*)(ws + off) = hv;
    *(f16x8*)(ws + WHI_TOTAL + off) = lv;
}

// ---------------------------------------------------------------------------
// Main kernel: one block = (batch, 64-point tile). 128 threads = 2 waves.
// Wave w computes 64 pts x 64 feats (2x2 tiles of 32x32 MFMA).
// X LDS layout: row = pt (256 B), 16B granule g stored at (g ^ (pt&15)).
// ---------------------------------------------------------------------------
__global__ __launch_bounds__(NTHR, 1) void siren_main(const float* __restrict__ xg,
                                                      const float* __restrict__ pg,
                                                      float* __restrict__ out,
                                                      const char* __restrict__ ws) {
    __shared__ __align__(16) _Float16 sXhi[TN * 128];
    __shared__ __align__(16) _Float16 sXlo[TN * 128];
    __shared__ __align__(16) _Float16 sW[2][2][IMG_BYTES / 2];  // [buf][hi/lo]
    __shared__ float sBias[3][128];
    __shared__ float sW1[256];
    __shared__ float sB1[128];
    __shared__ float sW5[390];   // 384 W5 + 3 b5

    const int t  = threadIdx.x;
    const int b  = blockIdx.y;
    const int n0 = blockIdx.x * TN;
    const float* p = pg + (size_t)b * NPARAM;

    // ---- stage small fp32 params (t in [0,128))
    sW1[t]        = p[OFF_W1 + t];
    sW1[128 + t]  = p[OFF_W1 + 128 + t];
    sB1[t]        = p[OFF_B1 + t];
    sBias[0][t]   = p[OFF_B2 + t];
    sBias[1][t]   = p[OFF_B3 + t];
    sBias[2][t]   = p[OFF_B4 + t];
    sW5[t]        = p[OFF_W5 + t];
    sW5[128 + t]  = p[OFF_W5 + 128 + t];
    sW5[256 + t]  = p[OFF_W5 + 256 + t];
    if (t < 3) sW5[384 + t] = p[OFF_B5 + t];

    const int pt1 = t & 63;
    const int fh  = t >> 6;
    float2 xy = ((const float2*)xg)[(size_t)b * N_ + n0 + pt1];

    __syncthreads();

    // ---- L1: 2 -> 128, fp32, sine, split to hi/lo, swizzled b128 stores
    {
        char* xhiB = (char*)sXhi;
        char* xloB = (char*)sXlo;
        int rowB = pt1 * 256;
        int sw   = pt1 & 15;
#pragma unroll
        for (int blk = 0; blk < 8; ++blk) {
            f16x8 hv, lv;
            int fbase = fh * 64 + blk * 8;
#pragma unroll
            for (int e = 0; e < 8; ++e) {
                int f = fbase + e;
                float a = fmaf(xy.x, sW1[2 * f], fmaf(xy.y, sW1[2 * f + 1], sB1[f]));
                float s = fast_sin30(a);
                _Float16 h = (_Float16)s;
                hv[e] = h;
                lv[e] = (_Float16)(s - (float)h);
            }
            int g = fh * 8 + blk;
            int pos = (g ^ sw) * 16;
            *(f16x8*)(xhiB + rowB + pos) = hv;
            *(f16x8*)(xloB + rowB + pos) = lv;
        }
    }

    // ---- MFMA lane constants
    const int lane = t & 63;
    const int wv   = t >> 6;
    const int f0   = wv * 64;
    const int mlan = lane & 31;
    const int grpA = lane >> 5;

    int ptRow[2], swA[2];
#pragma unroll
    for (int pp = 0; pp < 2; ++pp) {
        int pt = pp * 32 + mlan;
        ptRow[pp] = pt * 256;
        swA[pp]   = pt & 15;
    }
    int bOff[2];
#pragma unroll
    for (int q = 0; q < 2; ++q) {
        int jl = f0 + q * 32 + mlan;
        int pos = (((jl & 3) * 2) + grpA) ^ ((jl >> 2) & 7);
        bOff[q] = (jl >> 2) * 128 + pos * 16;   // constant across chunks
    }

    uint2 rh[4], rl[4];
    auto load_chunk = [&](int li_, int c_, bool lo_) {
        const char* srcH = ws + (((size_t)(b * 3 + li_) * 8 + c_) * IMG_BYTES);
#pragma unroll
        for (int r = 0; r < 4; ++r) rh[r] = *(const uint2*)(srcH + t * 8 + r * 1024);
        if (lo_) {
            const char* srcL = srcH + WHI_TOTAL;
#pragma unroll
            for (int r = 0; r < 4; ++r) rl[r] = *(const uint2*)(srcL + t * 8 + r * 1024);
        }
    };
    auto store_chunk = [&](int buf_, bool lo_) {
        uint2* dH = (uint2*)&sW[buf_][0][0];
#pragma unroll
        for (int r = 0; r < 4; ++r) dH[t + r * 128] = rh[r];
        if (lo_) {
            uint2* dL = (uint2*)&sW[buf_][1][0];
#pragma unroll
            for (int r = 0; r < 4; ++r) dL[t + r * 128] = rl[r];
        }
    };

    f32x16 acc[2][2];

    for (int li = 0; li < 3; ++li) {
        const bool split = (li < 2);     // L2, L3 use hi/lo 3-MFMA
        const bool wLo   = (li != 1);    // L3 output feeds plain-fp16 L4: hi only

#pragma unroll
        for (int pp = 0; pp < 2; ++pp)
#pragma unroll
            for (int q = 0; q < 2; ++q)
#pragma unroll
                for (int i = 0; i < 16; ++i) acc[pp][q][i] = 0.f;

        load_chunk(li, 0, split);
        store_chunk(0, split);
        __syncthreads();

        for (int c = 0; c < 8; ++c) {
            const int buf = c & 1;
            if (c < 7) load_chunk(li, c + 1, split);

            const char* wb  = (const char*)&sW[buf][0][0];
            const char* wbl = (const char*)&sW[buf][1][0];
            const char* xh  = (const char*)sXhi;
            const char* xl  = (const char*)sXlo;
            const int gA = 2 * c + grpA;

            f16x8 aH[2], aL[2], bH[2], bL[2];
#pragma unroll
            for (int pp = 0; pp < 2; ++pp) {
                int off = ptRow[pp] + ((gA ^ swA[pp]) * 16);
                aH[pp] = *(const f16x8*)(xh + off);
                if (split) aL[pp] = *(const f16x8*)(xl + off);
            }
#pragma unroll
            for (int q = 0; q < 2; ++q) {
                bH[q] = *(const f16x8*)(wb + bOff[q]);
                if (split) bL[q] = *(const f16x8*)(wbl + bOff[q]);
            }
#pragma unroll
            for (int pp = 0; pp < 2; ++pp)
#pragma unroll
                for (int q = 0; q < 2; ++q) {
                    acc[pp][q] = __builtin_amdgcn_mfma_f32_32x32x16_f16(aH[pp], bH[q], acc[pp][q], 0, 0, 0);
                    if (split) {
                        acc[pp][q] = __builtin_amdgcn_mfma_f32_32x32x16_f16(aH[pp], bL[q], acc[pp][q], 0, 0, 0);
                        acc[pp][q] = __builtin_amdgcn_mfma_f32_32x32x16_f16(aL[pp], bH[q], acc[pp][q], 0, 0, 0);
                    }
                }

            if (c < 7) store_chunk((c + 1) & 1, split);
            __syncthreads();
        }

        // ---- epilogue: bias + sin(30*), split, write back to X (swizzled)
#pragma unroll
        for (int pp = 0; pp < 2; ++pp) {
            int ptb = pp * 32 + grpA * 4;
#pragma unroll
            for (int q = 0; q < 2; ++q) {
                int feat = f0 + q * 32 + mlan;
                float bias = sBias[li][feat];
                int gf = (feat >> 3);
                int fo = (feat & 7) * 2;
#pragma unroll
                for (int r = 0; r < 16; ++r) {
                    int pt = ptb + (r & 3) + 8 * (r >> 2);
                    float s = fast_sin30(acc[pp][q][r] + bias);
                    _Float16 h = (_Float16)s;
                    int byteoff = pt * 256 + ((gf ^ (pt & 15)) * 16) + fo;
                    *(_Float16*)((char*)sXhi + byteoff) = h;
                    if (wLo) *(_Float16*)((char*)sXlo + byteoff) = (_Float16)(s - (float)h);
                }
            }
        }
        __syncthreads();
    }

    // ---- L5: 128 -> 3, fp32 from hi+lo reconstruct
    {
        int pt  = t & 63;
        int jsel = t >> 6;   // wave-uniform: wave0 -> j=0,1 ; wave1 -> j=2
        const char* xh = (const char*)sXhi;
        const char* xl = (const char*)sXlo;
        int rowB = pt * 256;
        int sw   = pt & 15;
        float a0 = 0.f, a1 = 0.f;
#pragma unroll
        for (int g = 0; g < 16; ++g) {
            int off = rowB + ((g ^ sw) * 16);
            f16x8 hv = *(const f16x8*)(xh + off);
            f16x8 lv = *(const f16x8*)(xl + off);
#pragma unroll
            for (int e = 0; e < 8; ++e) {
                float xv = (float)hv[e] + (float)lv[e];
                int k = g * 8 + e;
                if (jsel == 0) {
                    a0 = fmaf(xv, sW5[k], a0);
                    a1 = fmaf(xv, sW5[128 + k], a1);
                } else {
                    a0 = fmaf(xv, sW5[256 + k], a0);
                }
            }
        }
        size_t obase = ((size_t)b * N_ + n0 + pt) * 3;
        if (jsel == 0) {
            out[obase + 0] = a0 + sW5[384];
            out[obase + 1] = a1 + sW5[385];
        } else {
            out[obase + 2] = a0 + sW5[386];
        }
    }
}

extern "C" void kernel_launch(void* const* d_in, const int* in_sizes, int n_in,
                              void* d_out, int out_size, void* d_ws, size_t ws_size,
                              hipStream_t stream) {
    (void)in_sizes; (void)n_in; (void)out_size; (void)ws_size;
    const float* x = (const float*)d_in[0];
    const float* p = (const float*)d_in[1];
    float* o = (float*)d_out;
    char* ws = (char*)d_ws;   // needs 6,291,456 B

    siren_split<<<dim3(768), dim3(256), 0, stream>>>(p, ws);
    siren_main<<<dim3(N_ / TN, B_), dim3(NTHR), 0, stream>>>(x, p, o, ws);
}